// Round 1
// baseline (986.472 us; speedup 1.0000x reference)
//
#include <hip/hip_runtime.h>

#define D 128
#define BM 64
#define BK 16

// ---------------------------------------------------------------------------
// Kernel 1: edge scatter-add in INPUT feature space.
//   Agg[rel, dst, :] += inv_norm[rel, dst] * X[src, :]
// One wave (64 lanes) per edge; each lane handles 2 consecutive floats
// (128 floats per row). Hardware fp32 atomics (unsafeAtomicAdd ->
// global_atomic_add_f32 on gfx950).
// ---------------------------------------------------------------------------
__global__ __launch_bounds__(256) void scatter_kernel(
    const float* __restrict__ X, const float* __restrict__ inv_norm,
    const int* __restrict__ esrc, const int* __restrict__ edst,
    const int* __restrict__ erel, float* __restrict__ agg,
    int r0, int rc, int E, int N)
{
    const int lane = threadIdx.x & 63;
    const int wid  = (int)((blockIdx.x * blockDim.x + threadIdx.x) >> 6);
    const int nw   = (int)((gridDim.x * blockDim.x) >> 6);

    for (int e = wid; e < E; e += nw) {
        int rel = erel[e] - r0;
        if ((unsigned)rel >= (unsigned)rc) continue;   // wave-uniform branch
        const int src = esrc[e];
        const int dst = edst[e];
        const float s = inv_norm[(size_t)(rel + r0) * N + dst];
        const float2 v = ((const float2*)(X + ((size_t)src << 7)))[lane];
        float* p = agg + ((((size_t)rel * N + dst) << 7) + ((size_t)lane << 1));
        unsafeAtomicAdd(p,     v.x * s);
        unsafeAtomicAdd(p + 1, v.y * s);
    }
}

// ---------------------------------------------------------------------------
// Kernel 2: fused GEMM  out[n,:] = sum_r Agg[r,n,:] @ W[r]  (+ X[n,:] @ W0)
// Treated as a single N x K x 128 GEMM with K = rc*128 (+128 for the X/W0
// block). BM=64 rows/block, BN=128 (all cols), BK=16.
// 256 threads: each computes an 8x4 micro-tile (acc in float4).
// ---------------------------------------------------------------------------
__global__ __launch_bounds__(256) void gemm_kernel(
    const float* __restrict__ agg, const float* __restrict__ X,
    const float* __restrict__ Wp, const float* __restrict__ W0,
    float* __restrict__ out, int N, int rc, int include_x, int accumulate)
{
    __shared__ float As[BK][BM + 4];   // +4 pad: keeps float4 alignment, breaks bank stride
    __shared__ float Bs[BK][D];

    const int tid = threadIdx.x;
    const int tx  = tid & 31;          // 32 col-groups * 4 cols = 128
    const int ty  = tid >> 5;          // 8 row-groups * 8 rows = 64
    const int n0  = (int)blockIdx.x * BM;

    // A-tile load mapping: 64 rows x 16 k = 256 float4 (one per thread)
    const int nl = tid >> 2;           // 0..63 row
    const int kq = tid & 3;            // k-quad within BK
    // B-tile load mapping: 16 rows x 128 cols = 512 float4 (two per thread)
    const int brow = tid >> 4;         // 0..15
    const int bcq  = tid & 15;

    float4 acc[8];
#pragma unroll
    for (int i = 0; i < 8; ++i) acc[i] = make_float4(0.f, 0.f, 0.f, 0.f);

    const int KB = rc * 8 + (include_x ? 8 : 0);
    for (int kb = 0; kb < KB; ++kb) {
        const int k0 = kb * BK;
        const int rb = k0 >> 7;                 // which 128-col block of K
        const int d0 = (k0 & 127) + (kq << 2);  // feature offset within block

        // ---- stage A tile ----
        float4 av = make_float4(0.f, 0.f, 0.f, 0.f);
        const int n = n0 + nl;
        if (n < N) {
            const float* asrc = (rb < rc)
                ? agg + ((((size_t)rb * N + n) << 7) + d0)
                : X   + (((size_t)n << 7) + d0);
            av = *(const float4*)asrc;
        }
        As[(kq << 2) + 0][nl] = av.x;
        As[(kq << 2) + 1][nl] = av.y;
        As[(kq << 2) + 2][nl] = av.z;
        As[(kq << 2) + 3][nl] = av.w;

        // ---- stage B tile ----
        const float* bsrc = (rb < rc)
            ? Wp + (size_t)(k0 + brow) * D
            : W0 + (size_t)((k0 & 127) + brow) * D;
        const float4 b0 = *(const float4*)(bsrc + (bcq << 2));
        const float4 b1 = *(const float4*)(bsrc + ((bcq + 16) << 2));
        *(float4*)&Bs[brow][(bcq) << 2]      = b0;
        *(float4*)&Bs[brow][(bcq + 16) << 2] = b1;

        __syncthreads();

#pragma unroll
        for (int kk = 0; kk < BK; ++kk) {
            const float4 b  = *(const float4*)&Bs[kk][tx << 2];
            const float* ap = &As[kk][ty << 3];
            const float4 a0 = *(const float4*)(ap);
            const float4 a1 = *(const float4*)(ap + 4);
            const float ar[8] = {a0.x, a0.y, a0.z, a0.w, a1.x, a1.y, a1.z, a1.w};
#pragma unroll
            for (int i = 0; i < 8; ++i) {
                const float a = ar[i];
                acc[i].x = fmaf(a, b.x, acc[i].x);
                acc[i].y = fmaf(a, b.y, acc[i].y);
                acc[i].z = fmaf(a, b.z, acc[i].z);
                acc[i].w = fmaf(a, b.w, acc[i].w);
            }
        }
        __syncthreads();
    }

    // ---- epilogue ----
#pragma unroll
    for (int i = 0; i < 8; ++i) {
        const int row = n0 + (ty << 3) + i;
        if (row < N) {
            float* po = out + (((size_t)row << 7) + (tx << 2));
            float4 v = acc[i];
            if (accumulate) {
                const float4 o = *(const float4*)po;
                v.x += o.x; v.y += o.y; v.z += o.z; v.w += o.w;
            }
            *(float4*)po = v;
        }
    }
}

// ---------------------------------------------------------------------------
extern "C" void kernel_launch(void* const* d_in, const int* in_sizes, int n_in,
                              void* d_out, int out_size, void* d_ws, size_t ws_size,
                              hipStream_t stream) {
    const float* X        = (const float*)d_in[0];
    const float* W        = (const float*)d_in[1];
    const float* W0       = (const float*)d_in[2];
    const float* inv_norm = (const float*)d_in[3];
    const int*   esrc     = (const int*)d_in[4];
    const int*   edst     = (const int*)d_in[5];
    const int*   erel     = (const int*)d_in[6];
    float* out = (float*)d_out;

    const int N = in_sizes[0] / D;       // 50000
    const int E = in_sizes[4];           // 800000
    const int R = in_sizes[3] / N;       // 8

    const size_t per_rel = (size_t)N * D * sizeof(float);  // 25.6 MB
    int chunk = (int)(ws_size / per_rel);
    if (chunk > R) chunk = R;
    if (chunk < 1) chunk = 1;            // assume ws >= 25.6 MB

    float* agg = (float*)d_ws;
    const int gemm_blocks = (N + BM - 1) / BM;

    for (int r0 = 0; r0 < R; r0 += chunk) {
        const int rc = (R - r0 < chunk) ? (R - r0) : chunk;
        hipMemsetAsync(agg, 0, (size_t)rc * per_rel, stream);
        scatter_kernel<<<4096, 256, 0, stream>>>(
            X, inv_norm, esrc, edst, erel, agg, r0, rc, E, N);
        gemm_kernel<<<gemm_blocks, 256, 0, stream>>>(
            agg, X, W + (size_t)r0 * D * D, W0, out, N, rc,
            (r0 == 0) ? 1 : 0, (r0 > 0) ? 1 : 0);
    }
}

// Round 3
// 408.404 us; speedup vs baseline: 2.4154x; 2.4154x over previous
//
#include <hip/hip_runtime.h>

typedef __attribute__((ext_vector_type(8))) short short8;
typedef __attribute__((ext_vector_type(4))) float f32x4;

__device__ __forceinline__ unsigned short f2bf(float f) {
    unsigned u = __float_as_uint(f);
    u += 0x7FFF + ((u >> 16) & 1);          // round-to-nearest-even
    return (unsigned short)(u >> 16);
}

// ---------------------------------------------------------------------------
// 1) Histogram of edges over key = rel*N + dst
// ---------------------------------------------------------------------------
__global__ __launch_bounds__(256) void hist_kernel(
    const int* __restrict__ edst, const int* __restrict__ erel,
    int* __restrict__ counts, int E, int N)
{
    int i = blockIdx.x * 256 + threadIdx.x;
    const int stride = gridDim.x * 256;
    for (; i < E; i += stride)
        atomicAdd(&counts[erel[i] * N + edst[i]], 1);
}

// ---------------------------------------------------------------------------
// 2) Exclusive prefix scan over counts[KB]  (3 kernels, 1024 items/block)
// ---------------------------------------------------------------------------
__global__ __launch_bounds__(256) void scan1_kernel(
    const int* __restrict__ counts, int* __restrict__ blockSums, int KB)
{
    __shared__ int sd[256];
    const int t = threadIdx.x;
    const int base = blockIdx.x * 1024 + t * 4;
    int s = 0;
#pragma unroll
    for (int i = 0; i < 4; ++i) { int idx = base + i; if (idx < KB) s += counts[idx]; }
    sd[t] = s; __syncthreads();
    for (int off = 128; off > 0; off >>= 1) {
        if (t < off) sd[t] += sd[t + off];
        __syncthreads();
    }
    if (t == 0) blockSums[blockIdx.x] = sd[0];
}

__global__ __launch_bounds__(512) void scan2_kernel(int* blockSums, int nb)
{
    __shared__ int sd[512];
    const int t = threadIdx.x;
    const int v = (t < nb) ? blockSums[t] : 0;
    sd[t] = v; __syncthreads();
    for (int off = 1; off < 512; off <<= 1) {
        int x = (t >= off) ? sd[t - off] : 0;
        __syncthreads();
        sd[t] += x;
        __syncthreads();
    }
    if (t < nb) blockSums[t] = sd[t] - v;   // exclusive
}

__global__ __launch_bounds__(256) void scan3_kernel(
    const int* __restrict__ counts, const int* __restrict__ blockSums,
    int* __restrict__ offsets, int KB)
{
    __shared__ int sd[256];
    const int t = threadIdx.x;
    const int base = blockIdx.x * 1024 + t * 4;
    int c[4]; int s = 0;
#pragma unroll
    for (int i = 0; i < 4; ++i) { int idx = base + i; c[i] = (idx < KB) ? counts[idx] : 0; s += c[i]; }
    sd[t] = s; __syncthreads();
    for (int off = 1; off < 256; off <<= 1) {
        int x = (t >= off) ? sd[t - off] : 0;
        __syncthreads();
        sd[t] += x;
        __syncthreads();
    }
    int run = sd[t] - s + blockSums[blockIdx.x];
#pragma unroll
    for (int i = 0; i < 4; ++i) { int idx = base + i; if (idx < KB) offsets[idx] = run; run += c[i]; }
}

// ---------------------------------------------------------------------------
// 3) Scatter src indices into sorted order (counting sort fill).
//    Destroys offsets: afterwards offsets[key] == end of bucket.
// ---------------------------------------------------------------------------
__global__ __launch_bounds__(256) void scatter_fill_kernel(
    const int* __restrict__ esrc, const int* __restrict__ edst,
    const int* __restrict__ erel, int* __restrict__ offsets,
    int* __restrict__ sorted_src, int E, int N)
{
    int i = blockIdx.x * 256 + threadIdx.x;
    const int stride = gridDim.x * 256;
    for (; i < E; i += stride) {
        const int key = erel[i] * N + edst[i];
        const int pos = atomicAdd(&offsets[key], 1);
        sorted_src[pos] = esrc[i];
    }
}

// ---------------------------------------------------------------------------
// 4) Segmented aggregate: one wave per (rel,dst) bucket.
//    A[dst][rel*128 + j] = bf16( inv_norm[rel,dst] * sum_edges X[src][j] )
//    No atomics; every row written exactly once (zeros for empty buckets).
// ---------------------------------------------------------------------------
__global__ __launch_bounds__(256) void aggregate_kernel(
    const float* __restrict__ X, const float* __restrict__ inv_norm,
    const int* __restrict__ sorted_src, const int* __restrict__ counts,
    const int* __restrict__ bucket_end, unsigned short* __restrict__ A,
    int N, int KB, int R)
{
    const int wv = (int)((blockIdx.x * blockDim.x + threadIdx.x) >> 6);
    if (wv >= KB) return;
    const int lane = threadIdx.x & 63;
    const int end = bucket_end[wv];
    const int cnt = counts[wv];
    const int r = wv / N;
    const int dst = wv - r * N;
    const float s = inv_norm[wv];
    float ax = 0.f, ay = 0.f;
    for (int i = end - cnt; i < end; ++i) {
        const int src = sorted_src[i];
        const float2 v = ((const float2*)(X + ((size_t)src << 7)))[lane];
        ax += v.x; ay += v.y;
    }
    const unsigned int packed = (unsigned)f2bf(ax * s) | ((unsigned)f2bf(ay * s) << 16);
    const int ktot = (R + 1) * 128;
    *(unsigned int*)(A + (size_t)dst * ktot + r * 128 + lane * 2) = packed;
}

// ---------------------------------------------------------------------------
// 5) Cast X into A's last 128 columns; build Bt[n][k] = [W;W0]^T in bf16.
// ---------------------------------------------------------------------------
__global__ __launch_bounds__(256) void cast_kernel(
    const float* __restrict__ X, const float* __restrict__ W,
    const float* __restrict__ W0, unsigned short* __restrict__ A,
    unsigned short* __restrict__ Bt, int M, int R)
{
    const int ktot = (R + 1) * 128;
    const int nx = M * 32;                 // float4 chunks of X
    const int idx = blockIdx.x * 256 + threadIdx.x;
    if (idx < nx) {
        const int n = idx >> 5, j = (idx & 31) << 2;
        const float4 v = *(const float4*)(X + (size_t)n * 128 + j);
        uint2 p;
        p.x = (unsigned)f2bf(v.x) | ((unsigned)f2bf(v.y) << 16);
        p.y = (unsigned)f2bf(v.z) | ((unsigned)f2bf(v.w) << 16);
        *(uint2*)(A + (size_t)n * ktot + R * 128 + j) = p;
    } else if (idx < nx + 128 * ktot) {
        const int e = idx - nx;
        const int n = e / ktot;
        const int k = e - n * ktot;
        const float v = (k < R * 128) ? W[(size_t)k * 128 + n]
                                      : W0[(size_t)(k - R * 128) * 128 + n];
        Bt[(size_t)n * ktot + k] = f2bf(v);
    }
}

// ---------------------------------------------------------------------------
// 6) bf16 MFMA GEMM: out[M,128] = A[M,ktot] @ Bt[128,ktot]^T  (fp32 out)
//    128 threads = 2 waves, 32 rows/block, full 128 cols per block.
//    MFMA 16x16x32: A frag m=lane&15, k=quad*8+j; B frag n=lane&15, k=quad*8+j;
//    D: col=lane&15, row=quad*4+reg (verified layouts).
// ---------------------------------------------------------------------------
__global__ __launch_bounds__(128) void gemm_kernel(
    const unsigned short* __restrict__ A, const unsigned short* __restrict__ Bt,
    float* __restrict__ out, int M, int ktot)
{
    __shared__ unsigned short Bs[128][40];  // 32 k + 8 pad per row
    const int tid = threadIdx.x;
    const int wave = tid >> 6;
    const int lane = tid & 63;
    const int ln = lane & 15, quad = lane >> 4;
    const int m0 = blockIdx.x * 32 + wave * 16;
    int m = m0 + ln; if (m >= M) m = M - 1;            // clamp; stores guarded
    const unsigned short* Arow = A + (size_t)m * ktot;
    const unsigned short* Brow = Bt + (size_t)tid * ktot;

    f32x4 acc[8] = {};
    const int nsteps = ktot >> 5;
    for (int kb = 0; kb < nsteps; ++kb) {
        const int k0 = kb << 5;
        const short8 a  = *(const short8*)(Arow + k0 + quad * 8);   // global, 16B/lane
        const short8 b0 = *(const short8*)(Brow + k0);
        const short8 b1 = *(const short8*)(Brow + k0 + 8);
        const short8 b2 = *(const short8*)(Brow + k0 + 16);
        const short8 b3 = *(const short8*)(Brow + k0 + 24);
        __syncthreads();
        *(short8*)&Bs[tid][0]  = b0;
        *(short8*)&Bs[tid][8]  = b1;
        *(short8*)&Bs[tid][16] = b2;
        *(short8*)&Bs[tid][24] = b3;
        __syncthreads();
#pragma unroll
        for (int c = 0; c < 8; ++c) {
            const short8 b = *(const short8*)&Bs[c * 16 + ln][quad * 8];
            acc[c] = __builtin_amdgcn_mfma_f32_16x16x32_bf16(a, b, acc[c], 0, 0, 0);
        }
    }
#pragma unroll
    for (int c = 0; c < 8; ++c) {
#pragma unroll
        for (int rg = 0; rg < 4; ++rg) {
            const int row = m0 + quad * 4 + rg;
            if (row < M) out[(size_t)row * 128 + c * 16 + ln] = acc[c][rg];
        }
    }
}

// ---------------------------------------------------------------------------
extern "C" void kernel_launch(void* const* d_in, const int* in_sizes, int n_in,
                              void* d_out, int out_size, void* d_ws, size_t ws_size,
                              hipStream_t stream) {
    const float* X        = (const float*)d_in[0];
    const float* W        = (const float*)d_in[1];
    const float* W0       = (const float*)d_in[2];
    const float* inv_norm = (const float*)d_in[3];
    const int*   esrc     = (const int*)d_in[4];
    const int*   edst     = (const int*)d_in[5];
    const int*   erel     = (const int*)d_in[6];
    float* out = (float*)d_out;

    const int N  = in_sizes[0] / 128;     // 50000
    const int E  = in_sizes[4];           // 800000
    const int R  = in_sizes[3] / N;       // 8
    const int KB = R * N;                 // 400000 buckets
    const int ktot = (R + 1) * 128;       // 1152

    char* ws = (char*)d_ws;
    size_t off = 0;
    auto alloc = [&](size_t bytes) -> char* {
        char* p = ws + off; off = (off + bytes + 255) & ~(size_t)255; return p;
    };
    unsigned short* A         = (unsigned short*)alloc((size_t)N * ktot * 2);   // 115.2 MB
    unsigned short* Bt        = (unsigned short*)alloc((size_t)128 * ktot * 2); // 0.3 MB
    int*            counts    = (int*)alloc((size_t)KB * 4);                    // 1.6 MB
    int*            offsets   = (int*)alloc((size_t)KB * 4);                    // 1.6 MB
    int*            blockSums = (int*)alloc(512 * 4);
    int*            sorted    = (int*)alloc((size_t)E * 4);                     // 3.2 MB
    (void)ws_size;

    const int nScanBlocks = (KB + 1023) / 1024;   // 391 (<=512)

    hipMemsetAsync(counts, 0, (size_t)KB * 4, stream);
    hist_kernel<<<1024, 256, 0, stream>>>(edst, erel, counts, E, N);
    scan1_kernel<<<nScanBlocks, 256, 0, stream>>>(counts, blockSums, KB);
    scan2_kernel<<<1, 512, 0, stream>>>(blockSums, nScanBlocks);
    scan3_kernel<<<nScanBlocks, 256, 0, stream>>>(counts, blockSums, offsets, KB);
    scatter_fill_kernel<<<1024, 256, 0, stream>>>(esrc, edst, erel, offsets, sorted, E, N);
    aggregate_kernel<<<(KB + 3) / 4, 256, 0, stream>>>(X, inv_norm, sorted, counts, offsets, A, N, KB, R);
    cast_kernel<<<(N * 32 + 128 * ktot + 255) / 256, 256, 0, stream>>>(X, W, W0, A, Bt, N, R);
    gemm_kernel<<<(N + 31) / 32, 128, 0, stream>>>(A, Bt, out, N, ktot);
}